// Round 18
// baseline (162.753 us; speedup 1.0000x reference)
//
#include <hip/hip_runtime.h>
#include <math.h>

typedef short bf16x8 __attribute__((ext_vector_type(8)));
typedef float f32x4 __attribute__((ext_vector_type(4)));

#define BB 64
#define NN 512
#define NH 4
#define FI 16
#define FO 64
#define HD1 1024
#define HD2 512
#define ODIM 40

__device__ __forceinline__ unsigned short f2bf(float f) {
    unsigned u = __float_as_uint(f);
    u += 0x7fffu + ((u >> 16) & 1u);        // RNE
    return (unsigned short)(u >> 16);
}
__device__ __forceinline__ unsigned pack2(float a, float b) {
    return (unsigned)f2bf(a) | ((unsigned)f2bf(b) << 16);
}
// async global->LDS, 16B per lane; lds dest = wave-uniform base + lane*16
__device__ __forceinline__ void gload16(const void* g, void* l) {
    __builtin_amdgcn_global_load_lds(
        (const __attribute__((address_space(1))) unsigned int*)g,
        (__attribute__((address_space(3))) unsigned int*)l,
        16, 0, 0);
}

// ---------------- kernel 0: wa[h][i] = sum_o w[h][i][o] * a_{src,dst}[h][o] ----------------
__global__ void k_wa(const float* __restrict__ w, const float* __restrict__ a_src,
                     const float* __restrict__ a_dst, float* __restrict__ wa)
{
    int t = threadIdx.x;      // 0..63 = h*16+i
    int h = t >> 4;
    float s = 0.f, d = 0.f;
    for (int o = 0; o < FO; ++o) {
        float wv = w[t*FO + o];
        s = fmaf(wv, a_src[h*FO + o], s);
        d = fmaf(wv, a_dst[h*FO + o], d);
    }
    wa[t] = s; wa[64 + t] = d;
}

// ---------------- kernel 1: projection -> hpT (V-fragment-linear bf16), asrc/adst, gat ----------------
__global__ __launch_bounds__(256) void k_proj2(
    const float* __restrict__ x, const float* __restrict__ w,
    const float* __restrict__ bias, const float* __restrict__ wa,
    short* __restrict__ hpT,
    float* __restrict__ asrc, float* __restrict__ adst,
    float* __restrict__ gat)
{
    __shared__ float xS[64][20];
    __shared__ float gS[NH][64][64];
    int b = blockIdx.y;
    int n0 = blockIdx.x * 64;
    int t = threadIdx.x;
    int h = t >> 6, o = t & 63;
    {
        int n = t >> 2, q = t & 3;
        float4 v = *(const float4*)&x[((size_t)b*NN + n0 + n)*FI + q*4];
        *(float4*)&xS[n][q*4] = v;
    }
    float wreg[16];
#pragma unroll
    for (int i = 0; i < FI; ++i) wreg[i] = w[(h*FI + i)*FO + o];
    __syncthreads();

    short* hb = hpT + (size_t)b * (NH*FO*NN);
    for (int nc = 0; nc < 8; ++nc) {
        float acc[8];
#pragma unroll
        for (int k = 0; k < 8; ++k) {
            int n = nc*8 + k;
            float4 a0 = *(const float4*)&xS[n][0];
            float4 a1 = *(const float4*)&xS[n][4];
            float4 a2 = *(const float4*)&xS[n][8];
            float4 a3 = *(const float4*)&xS[n][12];
            float sA = fmaf(a0.x, wreg[0], fmaf(a0.y, wreg[1], fmaf(a0.z, wreg[2], a0.w*wreg[3])));
            float sB = fmaf(a1.x, wreg[4], fmaf(a1.y, wreg[5], fmaf(a1.z, wreg[6], a1.w*wreg[7])));
            float sC = fmaf(a2.x, wreg[8], fmaf(a2.y, wreg[9], fmaf(a2.z, wreg[10], a2.w*wreg[11])));
            float sD = fmaf(a3.x, wreg[12], fmaf(a3.y, wreg[13], fmaf(a3.z, wreg[14], a3.w*wreg[15])));
            float s = (sA + sB) + (sC + sD);
            acc[k] = s;
            gS[h][n][o] = s;
        }
        uint4 p;
        p.x = pack2(acc[0], acc[1]); p.y = pack2(acc[2], acc[3]);
        p.z = pack2(acc[4], acc[5]); p.w = pack2(acc[6], acc[7]);
        int jt = (n0 >> 5) + (nc >> 2);
        *(uint4*)&hb[(size_t)(jt*256 + h*64 + o)*32 + (nc & 3)*8] = p;
    }
    {
        int n = o;
        float vs = 0.f, vd = 0.f;
#pragma unroll
        for (int i = 0; i < FI; ++i) {
            float xv = xS[n][i];
            vs = fmaf(xv, wa[h*FI + i], vs);
            vd = fmaf(xv, wa[64 + h*FI + i], vd);
        }
        asrc[(size_t)(b*NH + h)*NN + n0 + n] = vs;
        adst[(size_t)(b*NH + h)*NN + n0 + n] = vd;
    }
    __syncthreads();
#pragma unroll
    for (int r = 0; r < 16; ++r) {
        int idx = t + r*256;
        int n = idx >> 6, oo = idx & 63;
        float g = bias[oo] + ((gS[0][n][oo] + gS[1][n][oo]) + (gS[2][n][oo] + gS[3][n][oo]));
        gat[((size_t)b*NN + n0 + n)*FO + oo] = g;
    }
}

// ---------------- kernel 2: MFMA attention, head-split + depth-1 reg prefetch of V and mask ----------------
__global__ __launch_bounds__(512, 2) void k_attn2(
    const short* __restrict__ hpT, const float* __restrict__ mask,
    const float* __restrict__ asrc, const float* __restrict__ adst,
    float* __restrict__ gat)
{
    __shared__ float dS[NH*NN];           // 8KB
    __shared__ float dmaxS[NH], dminS[NH];
    __shared__ float part[4*4*64*4];      // [wv4][ot][lane][4] f32 = 16KB
    int b = blockIdx.y;
    int i0blk = blockIdx.x * 64;
    int t = threadIdx.x;
#pragma unroll
    for (int r = 0; r < 4; ++r) {
        int idx = t + r*512;
        dS[idx] = adst[(size_t)b*(NH*NN) + idx];
    }
    __syncthreads();
    int wave = t >> 6, lane = t & 63;
    int wv4 = wave & 3, hh = (wave >> 2) * 2;   // head base: 0 or 2
    if (wave < 4) {
        float mx = -INFINITY, mn = INFINITY;
        const float* dh = &dS[wave*NN];
#pragma unroll
        for (int q = 0; q < 8; ++q) {
            float v = dh[lane*8 + q];
            mx = fmaxf(mx, v); mn = fminf(mn, v);
        }
#pragma unroll
        for (int off = 1; off < 64; off <<= 1) {
            mx = fmaxf(mx, __shfl_xor(mx, off));
            mn = fminf(mn, __shfl_xor(mn, off));
        }
        if (lane == 0) { dmaxS[wave] = mx; dminS[wave] = mn; }
    }
    __syncthreads();
    int li = lane & 15, kq = lane >> 4;
    int i = i0blk + wv4*16 + li;
    float s[2], m[2], Ssum[2];
#pragma unroll
    for (int h2 = 0; h2 < 2; ++h2) {
        int h = hh + h2;
        s[h2] = asrc[(size_t)(b*NH + h)*NN + i];
        float dm = s[h2] >= 0.f ? dmaxS[h] : dminS[h];
        float l = s[h2] * dm;
        m[h2] = fmaxf(l, 0.2f*l);     // global max over all j (monotone)
        Ssum[h2] = 0.f;
    }
    f32x4 accH[2][4];
#pragma unroll
    for (int h2 = 0; h2 < 2; ++h2)
#pragma unroll
        for (int ot = 0; ot < 4; ++ot) accH[h2][ot] = (f32x4)0.f;

    const float* mrow = &mask[((size_t)b*NN + i)*NN];
    const short* vb = hpT + (size_t)b * (NH*FO*NN);

    auto loadV = [&](bf16x8 (&vf)[2][4], int jt) {
#pragma unroll
        for (int h2 = 0; h2 < 2; ++h2)
#pragma unroll
            for (int ot = 0; ot < 4; ++ot)
                vf[h2][ot] = *(const bf16x8*)&vb[(size_t)(jt*256 + (hh+h2)*64 + ot*16 + li)*32 + kq*8];
    };
    auto compute = [&](int jt, bf16x8 (&vf)[2][4], float4 c0, float4 c1) {
        int j0 = jt*32;
        float mk[8] = {c0.x, c0.y, c0.z, c0.w, c1.x, c1.y, c1.z, c1.w};
#pragma unroll
        for (int h2 = 0; h2 < 2; ++h2) {
            int h = hh + h2;
            float4 d0 = *(const float4*)&dS[h*NN + j0 + kq*8];
            float4 d1 = *(const float4*)&dS[h*NN + j0 + kq*8 + 4];
            float dv[8] = {d0.x,d0.y,d0.z,d0.w,d1.x,d1.y,d1.z,d1.w};
            float u[8];
#pragma unroll
            for (int q = 0; q < 8; ++q) {
                float v = s[h2]*dv[q];
                v = fmaxf(v, 0.2f*v);
                u[q] = __expf(v - m[h2]);
            }
            Ssum[h2] += ((u[0]+u[1]) + (u[2]+u[3])) + ((u[4]+u[5]) + (u[6]+u[7]));
            union { bf16x8 v; unsigned uu[4]; } pf;
#pragma unroll
            for (int q = 0; q < 4; ++q)
                pf.uu[q] = pack2(u[2*q]*mk[2*q], u[2*q+1]*mk[2*q+1]);
            __builtin_amdgcn_s_setprio(1);
#pragma unroll
            for (int ot = 0; ot < 4; ++ot)
                accH[h2][ot] = __builtin_amdgcn_mfma_f32_16x16x32_bf16(pf.v, vf[h2][ot], accH[h2][ot], 0, 0, 0);
            __builtin_amdgcn_s_setprio(0);
        }
    };

    bf16x8 vfA[2][4], vfB[2][4];
    float4 mA0, mA1, mB0, mB1;
    loadV(vfA, 0);
    mA0 = *(const float4*)&mrow[kq*8];
    mA1 = *(const float4*)&mrow[kq*8 + 4];
    __builtin_amdgcn_sched_barrier(0);
    for (int jp = 0; jp < 8; ++jp) {
        int jt = jp*2;
        // issue next-jt V + mask, then compute current (loads in flight across compute)
        loadV(vfB, jt+1);
        mB0 = *(const float4*)&mrow[(jt+1)*32 + kq*8];
        mB1 = *(const float4*)&mrow[(jt+1)*32 + kq*8 + 4];
        __builtin_amdgcn_sched_barrier(0);
        compute(jt, vfA, mA0, mA1);
        if (jp < 7) {
            loadV(vfA, jt+2);
            mA0 = *(const float4*)&mrow[(jt+2)*32 + kq*8];
            mA1 = *(const float4*)&mrow[(jt+2)*32 + kq*8 + 4];
        }
        __builtin_amdgcn_sched_barrier(0);
        compute(jt+1, vfB, mB0, mB1);
    }
#pragma unroll
    for (int h2 = 0; h2 < 2; ++h2) {
        Ssum[h2] += __shfl_xor(Ssum[h2], 16);
        Ssum[h2] += __shfl_xor(Ssum[h2], 32);
    }
    float rinv[2][4];
#pragma unroll
    for (int h2 = 0; h2 < 2; ++h2)
#pragma unroll
        for (int g = 0; g < 4; ++g)
            rinv[h2][g] = 1.0f / __shfl(Ssum[h2], kq*4 + g);
    f32x4 contrib[4];
#pragma unroll
    for (int ot = 0; ot < 4; ++ot)
#pragma unroll
        for (int g = 0; g < 4; ++g)
            contrib[ot][g] = accH[0][ot][g]*rinv[0][g] + accH[1][ot][g]*rinv[1][g];
    if (wave < 4) {
#pragma unroll
        for (int ot = 0; ot < 4; ++ot) {
            float4 v = {contrib[ot][0], contrib[ot][1], contrib[ot][2], contrib[ot][3]};
            *(float4*)&part[((wv4*4 + ot)*64 + lane)*4] = v;
        }
    }
    __syncthreads();
    if (wave >= 4) {
#pragma unroll
        for (int ot = 0; ot < 4; ++ot) {
            float4 p = *(const float4*)&part[((wv4*4 + ot)*64 + lane)*4];
#pragma unroll
            for (int g = 0; g < 4; ++g) {
                int ii = i0blk + wv4*16 + kq*4 + g;
                int oo = ot*16 + li;
                size_t ix = ((size_t)b*NN + ii)*FO + oo;
                float pg = (g == 0) ? p.x : (g == 1) ? p.y : (g == 2) ? p.z : p.w;
                gat[ix] += contrib[ot][g] + pg;
            }
        }
    }
}

// ---------------- kernel 4a: weights -> bf16; W2 in FRAGMENT-LINEAR layout ----------------
__global__ __launch_bounds__(256) void k_conv(
    const float* __restrict__ W1, const float* __restrict__ W2, const float* __restrict__ W3,
    short* __restrict__ w1t, short* __restrict__ w2f, short* __restrict__ w3t)
{
    int idx = blockIdx.x * 256 + threadIdx.x;
    if (idx < HD1*FO) {
        int n = idx >> 6, k = idx & 63;
        w1t[idx] = (short)f2bf(W1[k*HD1 + n]);
    } else if (idx < HD1*FO + HD2*HD1) {
        int i2 = idx - HD1*FO;
        int e = i2 & 7, kqq = (i2 >> 3) & 3, n = (i2 >> 5) & 511, ks = i2 >> 14;
        int k = ks*32 + kqq*8 + e;
        w2f[i2] = (short)f2bf(W2[k*HD2 + n]);
    } else if (idx < HD1*FO + HD2*HD1 + 48*HD2) {
        int i3 = idx - (HD1*FO + HD2*HD1);
        int n = i3 >> 9, k = i3 & 511;
        w3t[i3] = (short)(n < ODIM ? f2bf(W3[k*ODIM + n]) : 0);
    }
}

// ---------------- kernel 4b: GEMM1 [32768x64]@[64x1024] -> relu -> h1g bf16 row-major ----------------
__global__ __launch_bounds__(256, 2) void k_mlpA(
    const float* __restrict__ gat,
    const short* __restrict__ w1t, const float* __restrict__ b1,
    short* __restrict__ h1g)
{
    __shared__ char a0b[8192];        // [64 m][64 k] bf16, XOR-swizzled
    int t = threadIdx.x;
    int lane = t & 63, wave = t >> 6;
    int li = lane & 15, kq = lane >> 4;
    int m0 = blockIdx.x * 64;

    {   // relu(gat) -> bf16 -> a0
        int row = t >> 2, c0 = (t & 3) * 16;
        const float4* g = (const float4*)&gat[(size_t)(m0 + row) * FO + c0];
        float4 v0 = g[0], v1 = g[1], v2 = g[2], v3 = g[3];
        uint4 p0, p1;
        p0.x = pack2(fmaxf(v0.x,0.f), fmaxf(v0.y,0.f));
        p0.y = pack2(fmaxf(v0.z,0.f), fmaxf(v0.w,0.f));
        p0.z = pack2(fmaxf(v1.x,0.f), fmaxf(v1.y,0.f));
        p0.w = pack2(fmaxf(v1.z,0.f), fmaxf(v1.w,0.f));
        p1.x = pack2(fmaxf(v2.x,0.f), fmaxf(v2.y,0.f));
        p1.y = pack2(fmaxf(v2.z,0.f), fmaxf(v2.w,0.f));
        p1.z = pack2(fmaxf(v3.x,0.f), fmaxf(v3.y,0.f));
        p1.w = pack2(fmaxf(v3.z,0.f), fmaxf(v3.w,0.f));
        int base = row*128 + c0*2;
        *(uint4*)(a0b + (base ^ ((row&7)<<4)))      = p0;
        *(uint4*)(a0b + ((base+16) ^ ((row&7)<<4))) = p1;
    }
    __syncthreads();

    for (int c = 0; c < 4; ++c) {     // wave owns 256 n-cols
        int n0 = wave * 256 + c * 64;
        f32x4 acc[4][4];
#pragma unroll
        for (int mt = 0; mt < 4; ++mt)
#pragma unroll
            for (int nt = 0; nt < 4; ++nt) acc[mt][nt] = (f32x4)0.f;
#pragma unroll
        for (int ks = 0; ks < 2; ++ks) {
            int k0 = ks * 32;
            bf16x8 xf[4];
#pragma unroll
            for (int mt = 0; mt < 4; ++mt) {
                int row = mt * 16 + li;
                int addr = (row * 128 + k0 * 2 + kq * 16) ^ ((row & 7) << 4);
                xf[mt] = *(bf16x8*)(a0b + addr);
            }
#pragma unroll
            for (int nt = 0; nt < 4; ++nt) {
                int col = n0 + nt * 16 + li;
                bf16x8 wf = *(const bf16x8*)(w1t + col * 64 + k0 + kq * 8);
#pragma unroll
                for (int mt = 0; mt < 4; ++mt)
                    acc[mt][nt] = __builtin_amdgcn_mfma_f32_16x16x32_bf16(wf, xf[mt], acc[mt][nt], 0, 0, 0);
            }
        }
#pragma unroll
        for (int mt = 0; mt < 4; ++mt)
#pragma unroll
            for (int nt = 0; nt < 4; ++nt) {
                int m = mt * 16 + li;
                int nb = n0 + nt * 16 + kq * 4;
                float4 bb = *(const float4*)&b1[nb];
                float v0 = fmaxf(acc[mt][nt][0] + bb.x, 0.f);
                float v1 = fmaxf(acc[mt][nt][1] + bb.y, 0.f);
                float v2 = fmaxf(acc[mt][nt][2] + bb.z, 0.f);
                float v3 = fmaxf(acc[mt][nt][3] + bb.w, 0.f);
                uint2 pw; pw.x = pack2(v0, v1); pw.y = pack2(v2, v3);
                *(uint2*)&h1g[(size_t)(m0 + m) * HD1 + nb] = pw;
            }
    }
}

// ---------------- kernel 4c: GEMM2 (h1s LDS dbuf + W2 reg-stream from L2) + GEMM3 ----------------
__global__ __launch_bounds__(512, 2) void k_mlpB(
    const short* __restrict__ h1g,
    const short* __restrict__ w2f, const float* __restrict__ b2,
    const short* __restrict__ w3t, const float* __restrict__ b3,
    float* __restrict__ out)
{
    extern __shared__ char smem[];    // 131072 B
    int t = threadIdx.x;
    int lane = t & 63, wave = t >> 6;
    int li = lane & 15, kq = lane >> 4;
    int m0 = blockIdx.x * 128;

    auto STAGE = [&](int i, int ks) {
        char* base = smem + i * 8192;
        int row = wave * 16 + (lane >> 2);
        int slotS = (lane & 3) ^ ((row >> 1) & 3);
        const short* src = h1g + (size_t)(m0 + row) * HD1 + ks * 32 + slotS * 8;
        gload16(src, base + wave * 1024);
    };
    const short* wfbase = w2f + ((size_t)(wave*64 + li)*4 + kq)*8;

    f32x4 acc2[8][4];
#pragma unroll
    for (int mt = 0; mt < 8; ++mt)
#pragma unroll
        for (int nt = 0; nt < 4; ++nt) acc2[mt][nt] = (f32x4)0.f;

    bf16x8 wf0[4], wf1[4];
    __builtin_amdgcn_sched_barrier(0);
    STAGE(0, 0);
#pragma unroll
    for (int nt = 0; nt < 4; ++nt) wf0[nt] = *(const bf16x8*)(wfbase + 0*16384 + nt*512);
    __builtin_amdgcn_sched_barrier(0);
    STAGE(1, 1);
#pragma unroll
    for (int nt = 0; nt < 4; ++nt) wf1[nt] = *(const bf16x8*)(wfbase + 1*16384 + nt*512);
    __builtin_amdgcn_sched_barrier(0);

    for (int ks = 0; ks < 32; ++ks) {
        int cur = ks & 1;
        if (ks < 31) { asm volatile("s_waitcnt vmcnt(5)" ::: "memory"); }
        else         { asm volatile("s_waitcnt vmcnt(0)" ::: "memory"); }
        __builtin_amdgcn_sched_barrier(0);
        __builtin_amdgcn_s_barrier();           // cur h1s fully staged (all waves)
        __builtin_amdgcn_sched_barrier(0);

        char* base = smem + cur * 8192;
        bf16x8 xf[8];
#pragma unroll
        for (int mt = 0; mt < 8; ++mt) {
            int m = mt * 16 + li;
            int slot = kq ^ ((m >> 1) & 3);
            xf[mt] = *(bf16x8*)(base + m * 64 + slot * 16);
        }
        asm volatile("s_waitcnt lgkmcnt(0)" ::: "memory");   // my reads in regs
        __builtin_amdgcn_sched_barrier(0);
        __builtin_amdgcn_s_barrier();           // ALL waves done reading cur
        __builtin_amdgcn_sched_barrier(0);

        bf16x8 wfn[4];
        if (ks < 30) {
            STAGE(cur, ks + 2);                 // group = {1 lds + 4 wf} = 5 VMEM
#pragma unroll
            for (int nt = 0; nt < 4; ++nt)
                wfn[nt] = *(const bf16x8*)(wfbase + (size_t)(ks+2)*16384 + nt*512);
        }
        __builtin_amdgcn_sched_barrier(0);

        __builtin_amdgcn_s_setprio(1);
#pragma unroll
        for (int nt = 0; nt < 4; ++nt)
#pragma unroll
            for (int mt = 0; mt < 8; ++mt)
                acc2[mt][nt] = __builtin_amdgcn_mfma_f32_16x16x32_bf16(wf0[nt], xf[mt], acc2[mt][nt], 0, 0, 0);
        __builtin_amdgcn_s_setprio(0);
        if (ks < 30) {
#pragma unroll
            for (int nt = 0; nt < 4; ++nt) { wf0[nt] = wf1[nt]; wf1[nt] = wfn[nt]; }
        } else {
#pragma unroll
            for (int nt = 0; nt < 4; ++nt) wf0[nt] = wf1[nt];
        }
    }
    __syncthreads();

    // ---- h2 = relu(acc2 + b2) -> bf16 -> LDS [128][512] swizzled (overwrites dbuf)
#pragma unroll
    for (int mt = 0; mt < 8; ++mt)
#pragma unroll
        for (int nt = 0; nt < 4; ++nt) {
            int m = mt * 16 + li;
            int nb = wave * 64 + nt * 16 + kq * 4;
            float4 bb = *(const float4*)&b2[nb];
            float v0 = fmaxf(acc2[mt][nt][0] + bb.x, 0.f);
            float v1 = fmaxf(acc2[mt][nt][1] + bb.y, 0.f);
            float v2 = fmaxf(acc2[mt][nt][2] + bb.z, 0.f);
            float v3 = fmaxf(acc2[mt][nt][3] + bb.w, 0.f);
            uint2 pw; pw.x = pack2(v0, v1); pw.y = pack2(v2, v3);
            int addr = (m * 1024 + nb * 2) ^ ((m & 7) << 4);
            *(uint2*)(smem + addr) = pw;
        }
    __syncthreads();

    // ---- GEMM3 [128x512]@[512x48]: wave owns 16 m-rows, full K
    f32x4 acc3[3];
#pragma unroll
    for (int nt = 0; nt < 3; ++nt) acc3[nt] = (f32x4)0.f;
#pragma unroll
    for (int ks = 0; ks < 16; ++ks) {
        int k0 = ks * 32;
        int m = wave * 16 + li;
        int addr = (m * 1024 + k0 * 2 + kq * 16) ^ ((m & 7) << 4);
        bf16x8 xfr = *(bf16x8*)(smem + addr);
#pragma unroll
        for (int nt = 0; nt < 3; ++nt) {
            int col = nt * 16 + li;
            bf16x8 wfr = *(const bf16x8*)(w3t + col * 512 + k0 + kq * 8);
            acc3[nt] = __builtin_amdgcn_mfma_f32_16x16x32_bf16(wfr, xfr, acc3[nt], 0, 0, 0);
        }
    }
#pragma unroll
    for (int nt = 0; nt < 3; ++nt)
#pragma unroll
        for (int g = 0; g < 4; ++g) {
            int n = nt * 16 + kq * 4 + g;
            if (n < ODIM) {
                int m = wave * 16 + li;
                float s = acc3[nt][g] + b3[n];
                s = 1.f / (1.f + __expf(-s));
                s = fminf(fmaxf(s, 0.01f), 0.99f);
                out[(size_t)(m0 + m) * ODIM + n] = s;
            }
        }
}

extern "C" void kernel_launch(void* const* d_in, const int* in_sizes, int n_in,
                              void* d_out, int out_size, void* d_ws, size_t ws_size,
                              hipStream_t stream)
{
    const float* x     = (const float*)d_in[0];
    const float* mask  = (const float*)d_in[1];
    const float* w     = (const float*)d_in[2];
    const float* a_src = (const float*)d_in[3];
    const float* a_dst = (const float*)d_in[4];
    const float* bias  = (const float*)d_in[5];
    const float* W1    = (const float*)d_in[6];
    const float* b1    = (const float*)d_in[7];
    const float* W2    = (const float*)d_in[8];
    const float* b2    = (const float*)d_in[9];
    const float* W3    = (const float*)d_in[10];
    const float* b3    = (const float*)d_in[11];
    float* out = (float*)d_out;

    char* p = (char*)d_ws;
    // h1g [32768][1024] bf16 (67.1MB) overlays hpT/asrc/adst (dead before k_mlpA)
    short* h1g = (short*)p;
    short* hpT = (short*)p;  p += (size_t)BB*NH*FO*NN*2;   // 16.78 MB
    float* asrc = (float*)p; p += (size_t)BB*NH*NN*4;
    float* adst = (float*)p; p += (size_t)BB*NH*NN*4;
    p = (char*)d_ws + (size_t)BB*NN*HD1*2;                 // past h1g (67.1 MB)
    float* gat  = (float*)p; p += (size_t)BB*NN*FO*4;      // 8.39 MB
    short* w1t  = (short*)p; p += (size_t)HD1*FO*2;
    short* w2f  = (short*)p; p += (size_t)HD2*HD1*2;
    short* w3t  = (short*)p; p += (size_t)48*HD2*2;
    float* wa   = (float*)p; p += 128*4;                   // total ~76.7 MB

    k_wa   <<<1, 64, 0, stream>>>(w, a_src, a_dst, wa);
    k_conv <<<(HD1*FO + HD2*HD1 + 48*HD2)/256, 256, 0, stream>>>(W1, W2, W3, w1t, w2f, w3t);
    k_proj2<<<dim3(NN/64, BB), 256, 0, stream>>>(x, w, bias, wa, hpT, asrc, adst, gat);
    k_attn2<<<dim3(NN/64, BB), 512, 0, stream>>>(hpT, mask, asrc, adst, gat);
    k_mlpA <<<BB*NN/64, 256, 0, stream>>>(gat, w1t, b1, h1g);
    k_mlpB <<<BB*NN/128, 512, 131072, stream>>>(h1g, w2f, b2, w3t, b3, out);
}

// Round 19
// 160.188 us; speedup vs baseline: 1.0160x; 1.0160x over previous
//
#include <hip/hip_runtime.h>
#include <math.h>

typedef short bf16x8 __attribute__((ext_vector_type(8)));
typedef float f32x4 __attribute__((ext_vector_type(4)));

#define BB 64
#define NN 512
#define NH 4
#define FI 16
#define FO 64
#define HD1 1024
#define HD2 512
#define ODIM 40

__device__ __forceinline__ unsigned short f2bf(float f) {
    unsigned u = __float_as_uint(f);
    u += 0x7fffu + ((u >> 16) & 1u);        // RNE
    return (unsigned short)(u >> 16);
}
__device__ __forceinline__ unsigned pack2(float a, float b) {
    return (unsigned)f2bf(a) | ((unsigned)f2bf(b) << 16);
}
// async global->LDS, 16B per lane; lds dest = wave-uniform base + lane*16
__device__ __forceinline__ void gload16(const void* g, void* l) {
    __builtin_amdgcn_global_load_lds(
        (const __attribute__((address_space(1))) unsigned int*)g,
        (__attribute__((address_space(3))) unsigned int*)l,
        16, 0, 0);
}

// ---------------- kernel 0: wa[h][i] = sum_o w[h][i][o] * a_{src,dst}[h][o] ----------------
__global__ void k_wa(const float* __restrict__ w, const float* __restrict__ a_src,
                     const float* __restrict__ a_dst, float* __restrict__ wa)
{
    int t = threadIdx.x;      // 0..63 = h*16+i
    int h = t >> 4;
    float s = 0.f, d = 0.f;
    for (int o = 0; o < FO; ++o) {
        float wv = w[t*FO + o];
        s = fmaf(wv, a_src[h*FO + o], s);
        d = fmaf(wv, a_dst[h*FO + o], d);
    }
    wa[t] = s; wa[64 + t] = d;
}

// ---------------- kernel 0b: bit-pack mask (streaming, coalesced) ----------------
// mbits[row][kq*16 + jt] byte holds bits q=0..7 for j = jt*32 + kq*8 + q.
__global__ __launch_bounds__(256) void k_pack(
    const float* __restrict__ mask, unsigned char* __restrict__ mbits)
{
    __shared__ unsigned char lb[4][64];
    int t = threadIdx.x;
    int r = t >> 6, l = t & 63;
    size_t R = (size_t)blockIdx.x * 4 + r;       // grid = BB*NN/4
    const float4* src = (const float4*)(mask + R*NN + l*8);
    float4 a = src[0], bq = src[1];
    unsigned byte = 0;
    byte |= (a.x  != 0.f) ? 1u   : 0u;
    byte |= (a.y  != 0.f) ? 2u   : 0u;
    byte |= (a.z  != 0.f) ? 4u   : 0u;
    byte |= (a.w  != 0.f) ? 8u   : 0u;
    byte |= (bq.x != 0.f) ? 16u  : 0u;
    byte |= (bq.y != 0.f) ? 32u  : 0u;
    byte |= (bq.z != 0.f) ? 64u  : 0u;
    byte |= (bq.w != 0.f) ? 128u : 0u;
    lb[r][(l & 3)*16 + (l >> 2)] = (unsigned char)byte;   // l = j/8: kq=l&3, jt=l>>2
    __syncthreads();
    if (t < 16) {
        int rr = t >> 2, seg = t & 3;
        uint4 v = *(uint4*)&lb[rr][seg*16];
        *(uint4*)&mbits[((size_t)blockIdx.x*4 + rr)*64 + seg*16] = v;
    }
}

// ---------------- kernel 1: projection -> hpT (V-fragment-linear bf16), asrc/adst, gat ----------------
__global__ __launch_bounds__(256) void k_proj2(
    const float* __restrict__ x, const float* __restrict__ w,
    const float* __restrict__ bias, const float* __restrict__ wa,
    short* __restrict__ hpT,
    float* __restrict__ asrc, float* __restrict__ adst,
    float* __restrict__ gat)
{
    __shared__ float xS[64][20];
    __shared__ float gS[NH][64][64];
    int b = blockIdx.y;
    int n0 = blockIdx.x * 64;
    int t = threadIdx.x;
    int h = t >> 6, o = t & 63;
    {
        int n = t >> 2, q = t & 3;
        float4 v = *(const float4*)&x[((size_t)b*NN + n0 + n)*FI + q*4];
        *(float4*)&xS[n][q*4] = v;
    }
    float wreg[16];
#pragma unroll
    for (int i = 0; i < FI; ++i) wreg[i] = w[(h*FI + i)*FO + o];
    __syncthreads();

    short* hb = hpT + (size_t)b * (NH*FO*NN);
    for (int nc = 0; nc < 8; ++nc) {
        float acc[8];
#pragma unroll
        for (int k = 0; k < 8; ++k) {
            int n = nc*8 + k;
            float4 a0 = *(const float4*)&xS[n][0];
            float4 a1 = *(const float4*)&xS[n][4];
            float4 a2 = *(const float4*)&xS[n][8];
            float4 a3 = *(const float4*)&xS[n][12];
            float sA = fmaf(a0.x, wreg[0], fmaf(a0.y, wreg[1], fmaf(a0.z, wreg[2], a0.w*wreg[3])));
            float sB = fmaf(a1.x, wreg[4], fmaf(a1.y, wreg[5], fmaf(a1.z, wreg[6], a1.w*wreg[7])));
            float sC = fmaf(a2.x, wreg[8], fmaf(a2.y, wreg[9], fmaf(a2.z, wreg[10], a2.w*wreg[11])));
            float sD = fmaf(a3.x, wreg[12], fmaf(a3.y, wreg[13], fmaf(a3.z, wreg[14], a3.w*wreg[15])));
            float s = (sA + sB) + (sC + sD);
            acc[k] = s;
            gS[h][n][o] = s;
        }
        uint4 p;
        p.x = pack2(acc[0], acc[1]); p.y = pack2(acc[2], acc[3]);
        p.z = pack2(acc[4], acc[5]); p.w = pack2(acc[6], acc[7]);
        int jt = (n0 >> 5) + (nc >> 2);
        *(uint4*)&hb[(size_t)(jt*256 + h*64 + o)*32 + (nc & 3)*8] = p;
    }
    {
        int n = o;
        float vs = 0.f, vd = 0.f;
#pragma unroll
        for (int i = 0; i < FI; ++i) {
            float xv = xS[n][i];
            vs = fmaf(xv, wa[h*FI + i], vs);
            vd = fmaf(xv, wa[64 + h*FI + i], vd);
        }
        asrc[(size_t)(b*NH + h)*NN + n0 + n] = vs;
        adst[(size_t)(b*NH + h)*NN + n0 + n] = vd;
    }
    __syncthreads();
#pragma unroll
    for (int r = 0; r < 16; ++r) {
        int idx = t + r*256;
        int n = idx >> 6, oo = idx & 63;
        float g = bias[oo] + ((gS[0][n][oo] + gS[1][n][oo]) + (gS[2][n][oo] + gS[3][n][oo]));
        gat[((size_t)b*NN + n0 + n)*FO + oo] = g;
    }
}

// ---------------- kernel 2: MFMA attention, head-split, BITMASK (one uint4 per lane) ----------------
__global__ __launch_bounds__(512, 2) void k_attn2(
    const short* __restrict__ hpT, const unsigned char* __restrict__ mbits,
    const float* __restrict__ asrc, const float* __restrict__ adst,
    float* __restrict__ gat)
{
    __shared__ float dS[NH*NN];           // 8KB
    __shared__ float dmaxS[NH], dminS[NH];
    __shared__ float part[4*4*64*4];      // [wv4][ot][lane][4] f32 = 16KB
    int b = blockIdx.y;
    int i0blk = blockIdx.x * 64;
    int t = threadIdx.x;
#pragma unroll
    for (int r = 0; r < 4; ++r) {
        int idx = t + r*512;
        dS[idx] = adst[(size_t)b*(NH*NN) + idx];
    }
    __syncthreads();
    int wave = t >> 6, lane = t & 63;
    int wv4 = wave & 3, hh = (wave >> 2) * 2;   // head base: 0 or 2
    if (wave < 4) {
        float mx = -INFINITY, mn = INFINITY;
        const float* dh = &dS[wave*NN];
#pragma unroll
        for (int q = 0; q < 8; ++q) {
            float v = dh[lane*8 + q];
            mx = fmaxf(mx, v); mn = fminf(mn, v);
        }
#pragma unroll
        for (int off = 1; off < 64; off <<= 1) {
            mx = fmaxf(mx, __shfl_xor(mx, off));
            mn = fminf(mn, __shfl_xor(mn, off));
        }
        if (lane == 0) { dmaxS[wave] = mx; dminS[wave] = mn; }
    }
    __syncthreads();
    int li = lane & 15, kq = lane >> 4;
    int i = i0blk + wv4*16 + li;
    float s[2], m[2], Ssum[2];
#pragma unroll
    for (int h2 = 0; h2 < 2; ++h2) {
        int h = hh + h2;
        s[h2] = asrc[(size_t)(b*NH + h)*NN + i];
        float dm = s[h2] >= 0.f ? dmaxS[h] : dminS[h];
        float l = s[h2] * dm;
        m[h2] = fmaxf(l, 0.2f*l);     // global max over all j (monotone)
        Ssum[h2] = 0.f;
    }
    f32x4 accH[2][4];
#pragma unroll
    for (int h2 = 0; h2 < 2; ++h2)
#pragma unroll
        for (int ot = 0; ot < 4; ++ot) accH[h2][ot] = (f32x4)0.f;

    // all mask bits for this lane's row+kq: one coalesced uint4
    unsigned mwarr[4];
    {
        uint4 mv = *(const uint4*)(mbits + ((size_t)(b*NN + i))*64 + kq*16);
        mwarr[0] = mv.x; mwarr[1] = mv.y; mwarr[2] = mv.z; mwarr[3] = mv.w;
    }
    const short* vb = hpT + (size_t)b * (NH*FO*NN);
#pragma unroll
    for (int jt = 0; jt < 16; ++jt) {
        unsigned mbyte = (mwarr[jt >> 2] >> ((jt & 3) * 8)) & 0xffu;
        int j0 = jt*32;
#pragma unroll
        for (int h2 = 0; h2 < 2; ++h2) {
            int h = hh + h2;
            float4 d0 = *(const float4*)&dS[h*NN + j0 + kq*8];
            float4 d1 = *(const float4*)&dS[h*NN + j0 + kq*8 + 4];
            float dv[8] = {d0.x,d0.y,d0.z,d0.w,d1.x,d1.y,d1.z,d1.w};
            float u[8];
#pragma unroll
            for (int q = 0; q < 8; ++q) {
                float v = s[h2]*dv[q];
                v = fmaxf(v, 0.2f*v);
                u[q] = __expf(v - m[h2]);
            }
            Ssum[h2] += ((u[0]+u[1]) + (u[2]+u[3])) + ((u[4]+u[5]) + (u[6]+u[7]));
            float mu[8];
#pragma unroll
            for (int q = 0; q < 8; ++q)
                mu[q] = ((mbyte >> q) & 1u) ? u[q] : 0.f;
            union { bf16x8 v; unsigned uu[4]; } pf;
#pragma unroll
            for (int q = 0; q < 4; ++q)
                pf.uu[q] = pack2(mu[2*q], mu[2*q+1]);
            __builtin_amdgcn_s_setprio(1);
#pragma unroll
            for (int ot = 0; ot < 4; ++ot) {
                bf16x8 vf = *(const bf16x8*)&vb[(size_t)(jt*256 + h*64 + ot*16 + li)*32 + kq*8];
                accH[h2][ot] = __builtin_amdgcn_mfma_f32_16x16x32_bf16(pf.v, vf, accH[h2][ot], 0, 0, 0);
            }
            __builtin_amdgcn_s_setprio(0);
        }
    }
#pragma unroll
    for (int h2 = 0; h2 < 2; ++h2) {
        Ssum[h2] += __shfl_xor(Ssum[h2], 16);
        Ssum[h2] += __shfl_xor(Ssum[h2], 32);
    }
    float rinv[2][4];
#pragma unroll
    for (int h2 = 0; h2 < 2; ++h2)
#pragma unroll
        for (int g = 0; g < 4; ++g)
            rinv[h2][g] = 1.0f / __shfl(Ssum[h2], kq*4 + g);
    f32x4 contrib[4];
#pragma unroll
    for (int ot = 0; ot < 4; ++ot)
#pragma unroll
        for (int g = 0; g < 4; ++g)
            contrib[ot][g] = accH[0][ot][g]*rinv[0][g] + accH[1][ot][g]*rinv[1][g];
    if (wave < 4) {
#pragma unroll
        for (int ot = 0; ot < 4; ++ot) {
            float4 v = {contrib[ot][0], contrib[ot][1], contrib[ot][2], contrib[ot][3]};
            *(float4*)&part[((wv4*4 + ot)*64 + lane)*4] = v;
        }
    }
    __syncthreads();
    if (wave >= 4) {
#pragma unroll
        for (int ot = 0; ot < 4; ++ot) {
            float4 p = *(const float4*)&part[((wv4*4 + ot)*64 + lane)*4];
#pragma unroll
            for (int g = 0; g < 4; ++g) {
                int ii = i0blk + wv4*16 + kq*4 + g;
                int oo = ot*16 + li;
                size_t ix = ((size_t)b*NN + ii)*FO + oo;
                float pg = (g == 0) ? p.x : (g == 1) ? p.y : (g == 2) ? p.z : p.w;
                gat[ix] += contrib[ot][g] + pg;
            }
        }
    }
}

// ---------------- kernel 4a: weights -> bf16; W2 in FRAGMENT-LINEAR layout ----------------
__global__ __launch_bounds__(256) void k_conv(
    const float* __restrict__ W1, const float* __restrict__ W2, const float* __restrict__ W3,
    short* __restrict__ w1t, short* __restrict__ w2f, short* __restrict__ w3t)
{
    int idx = blockIdx.x * 256 + threadIdx.x;
    if (idx < HD1*FO) {
        int n = idx >> 6, k = idx & 63;
        w1t[idx] = (short)f2bf(W1[k*HD1 + n]);
    } else if (idx < HD1*FO + HD2*HD1) {
        int i2 = idx - HD1*FO;
        int e = i2 & 7, kqq = (i2 >> 3) & 3, n = (i2 >> 5) & 511, ks = i2 >> 14;
        int k = ks*32 + kqq*8 + e;
        w2f[i2] = (short)f2bf(W2[k*HD2 + n]);
    } else if (idx < HD1*FO + HD2*HD1 + 48*HD2) {
        int i3 = idx - (HD1*FO + HD2*HD1);
        int n = i3 >> 9, k = i3 & 511;
        w3t[i3] = (short)(n < ODIM ? f2bf(W3[k*ODIM + n]) : 0);
    }
}

// ---------------- kernel 4b: GEMM1 [32768x64]@[64x1024] -> relu -> h1g bf16 row-major ----------------
__global__ __launch_bounds__(256, 2) void k_mlpA(
    const float* __restrict__ gat,
    const short* __restrict__ w1t, const float* __restrict__ b1,
    short* __restrict__ h1g)
{
    __shared__ char a0b[8192];        // [64 m][64 k] bf16, XOR-swizzled
    int t = threadIdx.x;
    int lane = t & 63, wave = t >> 6;
    int li = lane & 15, kq = lane >> 4;
    int m0 = blockIdx.x * 64;

    {   // relu(gat) -> bf16 -> a0
        int row = t >> 2, c0 = (t & 3) * 16;
        const float4* g = (const float4*)&gat[(size_t)(m0 + row) * FO + c0];
        float4 v0 = g[0], v1 = g[1], v2 = g[2], v3 = g[3];
        uint4 p0, p1;
        p0.x = pack2(fmaxf(v0.x,0.f), fmaxf(v0.y,0.f));
        p0.y = pack2(fmaxf(v0.z,0.f), fmaxf(v0.w,0.f));
        p0.z = pack2(fmaxf(v1.x,0.f), fmaxf(v1.y,0.f));
        p0.w = pack2(fmaxf(v1.z,0.f), fmaxf(v1.w,0.f));
        p1.x = pack2(fmaxf(v2.x,0.f), fmaxf(v2.y,0.f));
        p1.y = pack2(fmaxf(v2.z,0.f), fmaxf(v2.w,0.f));
        p1.z = pack2(fmaxf(v3.x,0.f), fmaxf(v3.y,0.f));
        p1.w = pack2(fmaxf(v3.z,0.f), fmaxf(v3.w,0.f));
        int base = row*128 + c0*2;
        *(uint4*)(a0b + (base ^ ((row&7)<<4)))      = p0;
        *(uint4*)(a0b + ((base+16) ^ ((row&7)<<4))) = p1;
    }
    __syncthreads();

    for (int c = 0; c < 4; ++c) {     // wave owns 256 n-cols
        int n0 = wave * 256 + c * 64;
        f32x4 acc[4][4];
#pragma unroll
        for (int mt = 0; mt < 4; ++mt)
#pragma unroll
            for (int nt = 0; nt < 4; ++nt) acc[mt][nt] = (f32x4)0.f;
#pragma unroll
        for (int ks = 0; ks < 2; ++ks) {
            int k0 = ks * 32;
            bf16x8 xf[4];
#pragma unroll
            for (int mt = 0; mt < 4; ++mt) {
                int row = mt * 16 + li;
                int addr = (row * 128 + k0 * 2 + kq * 16) ^ ((row & 7) << 4);
                xf[mt] = *(bf16x8*)(a0b + addr);
            }
#pragma unroll
            for (int nt = 0; nt < 4; ++nt) {
                int col = n0 + nt * 16 + li;
                bf16x8 wf = *(const bf16x8*)(w1t + col * 64 + k0 + kq * 8);
#pragma unroll
                for (int mt = 0; mt < 4; ++mt)
                    acc[mt][nt] = __builtin_amdgcn_mfma_f32_16x16x32_bf16(wf, xf[mt], acc[mt][nt], 0, 0, 0);
            }
        }
#pragma unroll
        for (int mt = 0; mt < 4; ++mt)
#pragma unroll
            for (int nt = 0; nt < 4; ++nt) {
                int m = mt * 16 + li;
                int nb = n0 + nt * 16 + kq * 4;
                float4 bb = *(const float4*)&b1[nb];
                float v0 = fmaxf(acc[mt][nt][0] + bb.x, 0.f);
                float v1 = fmaxf(acc[mt][nt][1] + bb.y, 0.f);
                float v2 = fmaxf(acc[mt][nt][2] + bb.z, 0.f);
                float v3 = fmaxf(acc[mt][nt][3] + bb.w, 0.f);
                uint2 pw; pw.x = pack2(v0, v1); pw.y = pack2(v2, v3);
                *(uint2*)&h1g[(size_t)(m0 + m) * HD1 + nb] = pw;
            }
    }
}

// ---------------- kernel 4c: GEMM2 (h1s LDS dbuf + W2 reg-stream from L2) + GEMM3 ----------------
__global__ __launch_bounds__(512, 2) void k_mlpB(
    const short* __restrict__ h1g,
    const short* __restrict__ w2f, const float* __restrict__ b2,
    const short* __restrict__ w3t, const float* __restrict__ b3,
    float* __restrict__ out)
{
    extern __shared__ char smem[];    // 131072 B
    int t = threadIdx.x;
    int lane = t & 63, wave = t >> 6;
    int li = lane & 15, kq = lane >> 4;
    int m0 = blockIdx.x * 128;

    auto STAGE = [&](int i, int ks) {
        char* base = smem + i * 8192;
        int row = wave * 16 + (lane >> 2);
        int slotS = (lane & 3) ^ ((row >> 1) & 3);
        const short* src = h1g + (size_t)(m0 + row) * HD1 + ks * 32 + slotS * 8;
        gload16(src, base + wave * 1024);
    };
    const short* wfbase = w2f + ((size_t)(wave*64 + li)*4 + kq)*8;

    f32x4 acc2[8][4];
#pragma unroll
    for (int mt = 0; mt < 8; ++mt)
#pragma unroll
        for (int nt = 0; nt < 4; ++nt) acc2[mt][nt] = (f32x4)0.f;

    bf16x8 wf0[4], wf1[4];
    __builtin_amdgcn_sched_barrier(0);
    STAGE(0, 0);
#pragma unroll
    for (int nt = 0; nt < 4; ++nt) wf0[nt] = *(const bf16x8*)(wfbase + 0*16384 + nt*512);
    __builtin_amdgcn_sched_barrier(0);
    STAGE(1, 1);
#pragma unroll
    for (int nt = 0; nt < 4; ++nt) wf1[nt] = *(const bf16x8*)(wfbase + 1*16384 + nt*512);
    __builtin_amdgcn_sched_barrier(0);

    for (int ks = 0; ks < 32; ++ks) {
        int cur = ks & 1;
        if (ks < 31) { asm volatile("s_waitcnt vmcnt(5)" ::: "memory"); }
        else         { asm volatile("s_waitcnt vmcnt(0)" ::: "memory"); }
        __builtin_amdgcn_sched_barrier(0);
        __builtin_amdgcn_s_barrier();           // cur h1s fully staged (all waves)
        __builtin_amdgcn_sched_barrier(0);

        char* base = smem + cur * 8192;
        bf16x8 xf[8];
#pragma unroll
        for (int mt = 0; mt < 8; ++mt) {
            int m = mt * 16 + li;
            int slot = kq ^ ((m >> 1) & 3);
            xf[mt] = *(bf16x8*)(base + m * 64 + slot * 16);
        }
        asm volatile("s_waitcnt lgkmcnt(0)" ::: "memory");   // my reads in regs
        __builtin_amdgcn_sched_barrier(0);
        __builtin_amdgcn_s_barrier();           // ALL waves done reading cur
        __builtin_amdgcn_sched_barrier(0);

        bf16x8 wfn[4];
        if (ks < 30) {
            STAGE(cur, ks + 2);                 // group = {1 lds + 4 wf} = 5 VMEM
#pragma unroll
            for (int nt = 0; nt < 4; ++nt)
                wfn[nt] = *(const bf16x8*)(wfbase + (size_t)(ks+2)*16384 + nt*512);
        }
        __builtin_amdgcn_sched_barrier(0);

        __builtin_amdgcn_s_setprio(1);
#pragma unroll
        for (int nt = 0; nt < 4; ++nt)
#pragma unroll
            for (int mt = 0; mt < 8; ++mt)
                acc2[mt][nt] = __builtin_amdgcn_mfma_f32_16x16x32_bf16(wf0[nt], xf[mt], acc2[mt][nt], 0, 0, 0);
        __builtin_amdgcn_s_setprio(0);
        if (ks < 30) {
#pragma unroll
            for (int nt = 0; nt < 4; ++nt) { wf0[nt] = wf1[nt]; wf1[nt] = wfn[nt]; }
        } else {
#pragma unroll
            for (int nt = 0; nt < 4; ++nt) wf0[nt] = wf1[nt];
        }
    }
    __syncthreads();

    // ---- h2 = relu(acc2 + b2) -> bf16 -> LDS [128][512] swizzled (overwrites dbuf)
#pragma unroll
    for (int mt = 0; mt < 8; ++mt)
#pragma unroll
        for (int nt = 0; nt < 4; ++nt) {
            int m = mt * 16 + li;
            int nb = wave * 64 + nt * 16 + kq * 4;
            float4 bb = *(const float4*)&b2[nb];
            float v0 = fmaxf(acc2[mt][nt][0] + bb.x, 0.f);
            float v1 = fmaxf(acc2[mt][nt][1] + bb.y, 0.f);
            float v2 = fmaxf(acc2[mt][nt][2] + bb.z, 0.f);
            float v3 = fmaxf(acc2[mt][nt][3] + bb.w, 0.f);
            uint2 pw; pw.x = pack2(v0, v1); pw.y = pack2(v2, v3);
            int addr = (m * 1024 + nb * 2) ^ ((m & 7) << 4);
            *(uint2*)(smem + addr) = pw;
        }
    __syncthreads();

    // ---- GEMM3 [128x512]@[512x48]: wave owns 16 m-rows, full K
    f32x4 acc3[3];
#pragma unroll
    for (int nt = 0; nt < 3; ++nt) acc3[nt] = (f32x4)0.f;
#pragma unroll
    for (int ks = 0; ks < 16; ++ks) {
        int k0 = ks * 32;
        int m = wave * 16 + li;
        int addr = (m * 1024 + k0 * 2 + kq * 16) ^ ((m & 7) << 4);
        bf16x8 xfr = *(bf16x8*)(smem + addr);
#pragma unroll
        for (int nt = 0; nt < 3; ++nt) {
            int col = nt * 16 + li;
            bf16x8 wfr = *(const bf16x8*)(w3t + col * 512 + k0 + kq * 8);
            acc3[nt] = __builtin_amdgcn_mfma_f32_16x16x32_bf16(wfr, xfr, acc3[nt], 0, 0, 0);
        }
    }
#pragma unroll
    for (int nt = 0; nt < 3; ++nt)
#pragma unroll
        for (int g = 0; g < 4; ++g) {
            int n = nt * 16 + kq * 4 + g;
            if (n < ODIM) {
                int m = wave * 16 + li;
                float s = acc3[nt][g] + b3[n];
                s = 1.f / (1.f + __expf(-s));
                s = fminf(fmaxf(s, 0.01f), 0.99f);
                out[(size_t)(m0 + m) * ODIM + n] = s;
            }
        }
}

extern "C" void kernel_launch(void* const* d_in, const int* in_sizes, int n_in,
                              void* d_out, int out_size, void* d_ws, size_t ws_size,
                              hipStream_t stream)
{
    const float* x     = (const float*)d_in[0];
    const float* mask  = (const float*)d_in[1];
    const float* w     = (const float*)d_in[2];
    const float* a_src = (const float*)d_in[3];
    const float* a_dst = (const float*)d_in[4];
    const float* bias  = (const float*)d_in[5];
    const float* W1    = (const float*)d_in[6];
    const float* b1    = (const float*)d_in[7];
    const float* W2    = (const float*)d_in[8];
    const float* b2    = (const float*)d_in[9];
    const float* W3    = (const float*)d_in[10];
    const float* b3    = (const float*)d_in[11];
    float* out = (float*)d_out;

    char* p = (char*)d_ws;
    // h1g [32768][1024] bf16 (67.1MB) overlays hpT/asrc/adst (dead before k_mlpA)
    short* h1g = (short*)p;
    short* hpT = (short*)p;  p += (size_t)BB*NH*FO*NN*2;   // 16.78 MB
    float* asrc = (float*)p; p += (size_t)BB*NH*NN*4;
    float* adst = (float*)p; p += (size_t)BB*NH*NN*4;
    p = (char*)d_ws + (size_t)BB*NN*HD1*2;                 // past h1g (67.1 MB)
    float* gat  = (float*)p; p += (size_t)BB*NN*FO*4;      // 8.39 MB
    short* w1t  = (short*)p; p += (size_t)HD1*FO*2;
    short* w2f  = (short*)p; p += (size_t)HD2*HD1*2;
    short* w3t  = (short*)p; p += (size_t)48*HD2*2;
    float* wa   = (float*)p; p += 128*4;
    unsigned char* mbits = (unsigned char*)p; p += (size_t)BB*NN*64;  // 2.1 MB; total ~79 MB

    k_wa   <<<1, 64, 0, stream>>>(w, a_src, a_dst, wa);
    k_pack <<<BB*NN/4, 256, 0, stream>>>(mask, mbits);
    k_conv <<<(HD1*FO + HD2*HD1 + 48*HD2)/256, 256, 0, stream>>>(W1, W2, W3, w1t, w2f, w3t);
    k_proj2<<<dim3(NN/64, BB), 256, 0, stream>>>(x, w, bias, wa, hpT, asrc, adst, gat);
    k_attn2<<<dim3(NN/64, BB), 512, 0, stream>>>(hpT, mbits, asrc, adst, gat);
    k_mlpA <<<BB*NN/64, 256, 0, stream>>>(gat, w1t, b1, h1g);
    k_mlpB <<<BB*NN/128, 512, 131072, stream>>>(h1g, w2f, b2, w3t, b3, out);
}

// Round 20
// 156.922 us; speedup vs baseline: 1.0372x; 1.0208x over previous
//
#include <hip/hip_runtime.h>
#include <math.h>

typedef short bf16x8 __attribute__((ext_vector_type(8)));
typedef float f32x4 __attribute__((ext_vector_type(4)));

#define BB 64
#define NN 512
#define NH 4
#define FI 16
#define FO 64
#define HD1 1024
#define HD2 512
#define ODIM 40

__device__ __forceinline__ unsigned short f2bf(float f) {
    unsigned u = __float_as_uint(f);
    u += 0x7fffu + ((u >> 16) & 1u);        // RNE
    return (unsigned short)(u >> 16);
}
__device__ __forceinline__ unsigned pack2(float a, float b) {
    return (unsigned)f2bf(a) | ((unsigned)f2bf(b) << 16);
}

// ---------------- kernel 0: wa[h][i] = sum_o w[h][i][o] * a_{src,dst}[h][o] ----------------
__global__ void k_wa(const float* __restrict__ w, const float* __restrict__ a_src,
                     const float* __restrict__ a_dst, float* __restrict__ wa)
{
    int t = threadIdx.x;      // 0..63 = h*16+i
    int h = t >> 4;
    float s = 0.f, d = 0.f;
    for (int o = 0; o < FO; ++o) {
        float wv = w[t*FO + o];
        s = fmaf(wv, a_src[h*FO + o], s);
        d = fmaf(wv, a_dst[h*FO + o], d);
    }
    wa[t] = s; wa[64 + t] = d;
}

// ---------------- kernel 0b: bit-pack mask (streaming, coalesced) ----------------
__global__ __launch_bounds__(256) void k_pack(
    const float* __restrict__ mask, unsigned char* __restrict__ mbits)
{
    __shared__ unsigned char lb[4][64];
    int t = threadIdx.x;
    int r = t >> 6, l = t & 63;
    size_t R = (size_t)blockIdx.x * 4 + r;       // grid = BB*NN/4
    const float4* src = (const float4*)(mask + R*NN + l*8);
    float4 a = src[0], bq = src[1];
    unsigned byte = 0;
    byte |= (a.x  != 0.f) ? 1u   : 0u;
    byte |= (a.y  != 0.f) ? 2u   : 0u;
    byte |= (a.z  != 0.f) ? 4u   : 0u;
    byte |= (a.w  != 0.f) ? 8u   : 0u;
    byte |= (bq.x != 0.f) ? 16u  : 0u;
    byte |= (bq.y != 0.f) ? 32u  : 0u;
    byte |= (bq.z != 0.f) ? 64u  : 0u;
    byte |= (bq.w != 0.f) ? 128u : 0u;
    lb[r][(l & 3)*16 + (l >> 2)] = (unsigned char)byte;
    __syncthreads();
    if (t < 16) {
        int rr = t >> 2, seg = t & 3;
        uint4 v = *(uint4*)&lb[rr][seg*16];
        *(uint4*)&mbits[((size_t)blockIdx.x*4 + rr)*64 + seg*16] = v;
    }
}

// ---------------- kernel 1: projection -> hpT (V-fragment-linear bf16), asrc/adst, gat ----------------
__global__ __launch_bounds__(256) void k_proj2(
    const float* __restrict__ x, const float* __restrict__ w,
    const float* __restrict__ bias, const float* __restrict__ wa,
    short* __restrict__ hpT,
    float* __restrict__ asrc, float* __restrict__ adst,
    float* __restrict__ gat)
{
    __shared__ float xS[64][20];
    __shared__ float gS[NH][64][64];
    int b = blockIdx.y;
    int n0 = blockIdx.x * 64;
    int t = threadIdx.x;
    int h = t >> 6, o = t & 63;
    {
        int n = t >> 2, q = t & 3;
        float4 v = *(const float4*)&x[((size_t)b*NN + n0 + n)*FI + q*4];
        *(float4*)&xS[n][q*4] = v;
    }
    float wreg[16];
#pragma unroll
    for (int i = 0; i < FI; ++i) wreg[i] = w[(h*FI + i)*FO + o];
    __syncthreads();

    short* hb = hpT + (size_t)b * (NH*FO*NN);
    for (int nc = 0; nc < 8; ++nc) {
        float acc[8];
#pragma unroll
        for (int k = 0; k < 8; ++k) {
            int n = nc*8 + k;
            float4 a0 = *(const float4*)&xS[n][0];
            float4 a1 = *(const float4*)&xS[n][4];
            float4 a2 = *(const float4*)&xS[n][8];
            float4 a3 = *(const float4*)&xS[n][12];
            float sA = fmaf(a0.x, wreg[0], fmaf(a0.y, wreg[1], fmaf(a0.z, wreg[2], a0.w*wreg[3])));
            float sB = fmaf(a1.x, wreg[4], fmaf(a1.y, wreg[5], fmaf(a1.z, wreg[6], a1.w*wreg[7])));
            float sC = fmaf(a2.x, wreg[8], fmaf(a2.y, wreg[9], fmaf(a2.z, wreg[10], a2.w*wreg[11])));
            float sD = fmaf(a3.x, wreg[12], fmaf(a3.y, wreg[13], fmaf(a3.z, wreg[14], a3.w*wreg[15])));
            float s = (sA + sB) + (sC + sD);
            acc[k] = s;
            gS[h][n][o] = s;
        }
        uint4 p;
        p.x = pack2(acc[0], acc[1]); p.y = pack2(acc[2], acc[3]);
        p.z = pack2(acc[4], acc[5]); p.w = pack2(acc[6], acc[7]);
        int jt = (n0 >> 5) + (nc >> 2);
        *(uint4*)&hb[(size_t)(jt*256 + h*64 + o)*32 + (nc & 3)*8] = p;
    }
    {
        int n = o;
        float vs = 0.f, vd = 0.f;
#pragma unroll
        for (int i = 0; i < FI; ++i) {
            float xv = xS[n][i];
            vs = fmaf(xv, wa[h*FI + i], vs);
            vd = fmaf(xv, wa[64 + h*FI + i], vd);
        }
        asrc[(size_t)(b*NH + h)*NN + n0 + n] = vs;
        adst[(size_t)(b*NH + h)*NN + n0 + n] = vd;
    }
    __syncthreads();
#pragma unroll
    for (int r = 0; r < 16; ++r) {
        int idx = t + r*256;
        int n = idx >> 6, oo = idx & 63;
        float g = bias[oo] + ((gS[0][n][oo] + gS[1][n][oo]) + (gS[2][n][oo] + gS[3][n][oo]));
        gat[((size_t)b*NN + n0 + n)*FO + oo] = g;
    }
}

// ---------------- kernel 2: MFMA attention, head-split, BITMASK (one uint4 per lane) ----------------
__global__ __launch_bounds__(512, 2) void k_attn2(
    const short* __restrict__ hpT, const unsigned char* __restrict__ mbits,
    const float* __restrict__ asrc, const float* __restrict__ adst,
    float* __restrict__ gat)
{
    __shared__ float dS[NH*NN];           // 8KB
    __shared__ float dmaxS[NH], dminS[NH];
    __shared__ float part[4*4*64*4];      // 16KB
    int b = blockIdx.y;
    int i0blk = blockIdx.x * 64;
    int t = threadIdx.x;
#pragma unroll
    for (int r = 0; r < 4; ++r) {
        int idx = t + r*512;
        dS[idx] = adst[(size_t)b*(NH*NN) + idx];
    }
    __syncthreads();
    int wave = t >> 6, lane = t & 63;
    int wv4 = wave & 3, hh = (wave >> 2) * 2;
    if (wave < 4) {
        float mx = -INFINITY, mn = INFINITY;
        const float* dh = &dS[wave*NN];
#pragma unroll
        for (int q = 0; q < 8; ++q) {
            float v = dh[lane*8 + q];
            mx = fmaxf(mx, v); mn = fminf(mn, v);
        }
#pragma unroll
        for (int off = 1; off < 64; off <<= 1) {
            mx = fmaxf(mx, __shfl_xor(mx, off));
            mn = fminf(mn, __shfl_xor(mn, off));
        }
        if (lane == 0) { dmaxS[wave] = mx; dminS[wave] = mn; }
    }
    __syncthreads();
    int li = lane & 15, kq = lane >> 4;
    int i = i0blk + wv4*16 + li;
    float s[2], m[2], Ssum[2];
#pragma unroll
    for (int h2 = 0; h2 < 2; ++h2) {
        int h = hh + h2;
        s[h2] = asrc[(size_t)(b*NH + h)*NN + i];
        float dm = s[h2] >= 0.f ? dmaxS[h] : dminS[h];
        float l = s[h2] * dm;
        m[h2] = fmaxf(l, 0.2f*l);
        Ssum[h2] = 0.f;
    }
    f32x4 accH[2][4];
#pragma unroll
    for (int h2 = 0; h2 < 2; ++h2)
#pragma unroll
        for (int ot = 0; ot < 4; ++ot) accH[h2][ot] = (f32x4)0.f;

    unsigned mwarr[4];
    {
        uint4 mv = *(const uint4*)(mbits + ((size_t)(b*NN + i))*64 + kq*16);
        mwarr[0] = mv.x; mwarr[1] = mv.y; mwarr[2] = mv.z; mwarr[3] = mv.w;
    }
    const short* vb = hpT + (size_t)b * (NH*FO*NN);
#pragma unroll
    for (int jt = 0; jt < 16; ++jt) {
        unsigned mbyte = (mwarr[jt >> 2] >> ((jt & 3) * 8)) & 0xffu;
        int j0 = jt*32;
#pragma unroll
        for (int h2 = 0; h2 < 2; ++h2) {
            int h = hh + h2;
            float4 d0 = *(const float4*)&dS[h*NN + j0 + kq*8];
            float4 d1 = *(const float4*)&dS[h*NN + j0 + kq*8 + 4];
            float dv[8] = {d0.x,d0.y,d0.z,d0.w,d1.x,d1.y,d1.z,d1.w};
            float u[8];
#pragma unroll
            for (int q = 0; q < 8; ++q) {
                float v = s[h2]*dv[q];
                v = fmaxf(v, 0.2f*v);
                u[q] = __expf(v - m[h2]);
            }
            Ssum[h2] += ((u[0]+u[1]) + (u[2]+u[3])) + ((u[4]+u[5]) + (u[6]+u[7]));
            float mu[8];
#pragma unroll
            for (int q = 0; q < 8; ++q)
                mu[q] = ((mbyte >> q) & 1u) ? u[q] : 0.f;
            union { bf16x8 v; unsigned uu[4]; } pf;
#pragma unroll
            for (int q = 0; q < 4; ++q)
                pf.uu[q] = pack2(mu[2*q], mu[2*q+1]);
            __builtin_amdgcn_s_setprio(1);
#pragma unroll
            for (int ot = 0; ot < 4; ++ot) {
                bf16x8 vf = *(const bf16x8*)&vb[(size_t)(jt*256 + h*64 + ot*16 + li)*32 + kq*8];
                accH[h2][ot] = __builtin_amdgcn_mfma_f32_16x16x32_bf16(pf.v, vf, accH[h2][ot], 0, 0, 0);
            }
            __builtin_amdgcn_s_setprio(0);
        }
    }
#pragma unroll
    for (int h2 = 0; h2 < 2; ++h2) {
        Ssum[h2] += __shfl_xor(Ssum[h2], 16);
        Ssum[h2] += __shfl_xor(Ssum[h2], 32);
    }
    float rinv[2][4];
#pragma unroll
    for (int h2 = 0; h2 < 2; ++h2)
#pragma unroll
        for (int g = 0; g < 4; ++g)
            rinv[h2][g] = 1.0f / __shfl(Ssum[h2], kq*4 + g);
    f32x4 contrib[4];
#pragma unroll
    for (int ot = 0; ot < 4; ++ot)
#pragma unroll
        for (int g = 0; g < 4; ++g)
            contrib[ot][g] = accH[0][ot][g]*rinv[0][g] + accH[1][ot][g]*rinv[1][g];
    if (wave < 4) {
#pragma unroll
        for (int ot = 0; ot < 4; ++ot) {
            float4 v = {contrib[ot][0], contrib[ot][1], contrib[ot][2], contrib[ot][3]};
            *(float4*)&part[((wv4*4 + ot)*64 + lane)*4] = v;
        }
    }
    __syncthreads();
    if (wave >= 4) {
#pragma unroll
        for (int ot = 0; ot < 4; ++ot) {
            float4 p = *(const float4*)&part[((wv4*4 + ot)*64 + lane)*4];
#pragma unroll
            for (int g = 0; g < 4; ++g) {
                int ii = i0blk + wv4*16 + kq*4 + g;
                int oo = ot*16 + li;
                size_t ix = ((size_t)b*NN + ii)*FO + oo;
                float pg = (g == 0) ? p.x : (g == 1) ? p.y : (g == 2) ? p.z : p.w;
                gat[ix] += contrib[ot][g] + pg;
            }
        }
    }
}

// ---------------- kernel 4a: weights -> bf16; W2 in FRAGMENT-LINEAR layout ----------------
__global__ __launch_bounds__(256) void k_conv(
    const float* __restrict__ W1, const float* __restrict__ W2, const float* __restrict__ W3,
    short* __restrict__ w1t, short* __restrict__ w2f, short* __restrict__ w3t)
{
    int idx = blockIdx.x * 256 + threadIdx.x;
    if (idx < HD1*FO) {
        int n = idx >> 6, k = idx & 63;
        w1t[idx] = (short)f2bf(W1[k*HD1 + n]);
    } else if (idx < HD1*FO + HD2*HD1) {
        int i2 = idx - HD1*FO;
        int e = i2 & 7, kqq = (i2 >> 3) & 3, n = (i2 >> 5) & 511, ks = i2 >> 14;
        int k = ks*32 + kqq*8 + e;
        w2f[i2] = (short)f2bf(W2[k*HD2 + n]);
    } else if (idx < HD1*FO + HD2*HD1 + 48*HD2) {
        int i3 = idx - (HD1*FO + HD2*HD1);
        int n = i3 >> 9, k = i3 & 511;
        w3t[i3] = (short)(n < ODIM ? f2bf(W3[k*ODIM + n]) : 0);
    }
}

// ---------------- kernel 4: FUSED MLP: GEMM1 on-the-fly + GEMM2 + GEMM3 ----------------
// a0 = relu(gat)->bf16 [128][64] LDS (16KB). Per K-step: each wave produces its 16-row
// h1 slice (4 MFMA from a0+w1t) into h1s dbuf (2x8KB); consumption loop unchanged.
// No h1g intermediate, no mlpA kernel.
__global__ __launch_bounds__(512, 2) void k_mlpB(
    const float* __restrict__ gat,
    const short* __restrict__ w1t, const float* __restrict__ b1,
    const short* __restrict__ w2f, const float* __restrict__ b2,
    const short* __restrict__ w3t, const float* __restrict__ b3,
    float* __restrict__ out)
{
    extern __shared__ char smem[];    // 131072 B; loop uses first 32KB (a0 16K + dbuf 16K)
    char* a0b = smem;
    char* h1s = smem + 16384;
    int t = threadIdx.x;
    int lane = t & 63, wave = t >> 6;
    int li = lane & 15, kq = lane >> 4;
    int m0 = blockIdx.x * 128;

    // ---- phase 0: relu(gat) -> bf16 -> a0 [128][64], swizzled (512 thr x 16 floats)
    {
        int row = t >> 2, c0 = (t & 3) * 16;
        const float4* g = (const float4*)&gat[(size_t)(m0 + row) * FO + c0];
        float4 v0 = g[0], v1 = g[1], v2 = g[2], v3 = g[3];
        uint4 p0, p1;
        p0.x = pack2(fmaxf(v0.x,0.f), fmaxf(v0.y,0.f));
        p0.y = pack2(fmaxf(v0.z,0.f), fmaxf(v0.w,0.f));
        p0.z = pack2(fmaxf(v1.x,0.f), fmaxf(v1.y,0.f));
        p0.w = pack2(fmaxf(v1.z,0.f), fmaxf(v1.w,0.f));
        p1.x = pack2(fmaxf(v2.x,0.f), fmaxf(v2.y,0.f));
        p1.y = pack2(fmaxf(v2.z,0.f), fmaxf(v2.w,0.f));
        p1.z = pack2(fmaxf(v3.x,0.f), fmaxf(v3.y,0.f));
        p1.w = pack2(fmaxf(v3.z,0.f), fmaxf(v3.w,0.f));
        int base = row*128 + c0*2;
        *(uint4*)(a0b + (base ^ ((row&7)<<4)))      = p0;
        *(uint4*)(a0b + ((base+16) ^ ((row&7)<<4))) = p1;
    }
    __syncthreads();

    // a0 fragments for this wave's m-tile (rows wave*16..+15), hoisted for the whole loop
    bf16x8 a0f[2];
#pragma unroll
    for (int k0s = 0; k0s < 2; ++k0s) {
        int row = wave*16 + li;
        int addr = (row*128 + k0s*64 + kq*16) ^ ((row&7)<<4);
        a0f[k0s] = *(bf16x8*)(a0b + addr);
    }

    // produce h1 slice [wave's 16 rows][32 k-outs of slice ks] into h1s buf
    auto PRODUCE = [&](int bufi, int ks) {
        char* hb = h1s + bufi*8192;
#pragma unroll
        for (int klt = 0; klt < 2; ++klt) {
            int n = ks*32 + klt*16 + li;
            bf16x8 w1f0 = *(const bf16x8*)(w1t + n*64 + kq*8);
            bf16x8 w1f1 = *(const bf16x8*)(w1t + n*64 + 32 + kq*8);
            f32x4 ah = (f32x4)0.f;
            ah = __builtin_amdgcn_mfma_f32_16x16x32_bf16(w1f0, a0f[0], ah, 0, 0, 0);
            ah = __builtin_amdgcn_mfma_f32_16x16x32_bf16(w1f1, a0f[1], ah, 0, 0, 0);
            int m = wave*16 + li;
            int nb = ks*32 + klt*16 + kq*4;
            float4 bb = *(const float4*)&b1[nb];
            float v0 = fmaxf(ah[0] + bb.x, 0.f);
            float v1 = fmaxf(ah[1] + bb.y, 0.f);
            float v2 = fmaxf(ah[2] + bb.z, 0.f);
            float v3 = fmaxf(ah[3] + bb.w, 0.f);
            uint2 pw; pw.x = pack2(v0, v1); pw.y = pack2(v2, v3);
            // logical 16B slot s0 holds k-elems s0*8..+8; physical slot = s0 ^ ((m>>1)&3)
            int s0 = klt*2 + (kq >> 1);
            int p = s0 ^ ((m >> 1) & 3);
            *(uint2*)(hb + m*64 + p*16 + (kq & 1)*8) = pw;
        }
    };

    const short* wfbase = w2f + ((size_t)(wave*64 + li)*4 + kq)*8;

    f32x4 acc2[8][4];
#pragma unroll
    for (int mt = 0; mt < 8; ++mt)
#pragma unroll
        for (int nt = 0; nt < 4; ++nt) acc2[mt][nt] = (f32x4)0.f;

    PRODUCE(0, 0);
    asm volatile("s_waitcnt lgkmcnt(0)" ::: "memory");
    __builtin_amdgcn_sched_barrier(0);
    __builtin_amdgcn_s_barrier();
    __builtin_amdgcn_sched_barrier(0);

    for (int ks = 0; ks < 32; ++ks) {
        int cur = ks & 1;
        // W2 fragments for this step (global, L2-resident; latency covered by PRODUCE+ds)
        bf16x8 wf[4];
#pragma unroll
        for (int nt = 0; nt < 4; ++nt)
            wf[nt] = *(const bf16x8*)(wfbase + (size_t)ks*16384 + nt*512);
        char* base = h1s + cur*8192;
        bf16x8 xfa[4];
#pragma unroll
        for (int mt = 0; mt < 4; ++mt) {
            int m = mt * 16 + li;
            int slot = kq ^ ((m >> 1) & 3);
            xfa[mt] = *(bf16x8*)(base + m * 64 + slot * 16);
        }
        if (ks < 31) PRODUCE(cur ^ 1, ks + 1);
        asm volatile("s_waitcnt lgkmcnt(0)" ::: "memory");   // xfa in regs; produce writes drained
        __builtin_amdgcn_sched_barrier(0);
        __builtin_amdgcn_s_setprio(1);
#pragma unroll
        for (int nt = 0; nt < 4; ++nt)
#pragma unroll
            for (int mt = 0; mt < 4; ++mt)
                acc2[mt][nt] = __builtin_amdgcn_mfma_f32_16x16x32_bf16(wf[nt], xfa[mt], acc2[mt][nt], 0, 0, 0);
        bf16x8 xfb[4];
#pragma unroll
        for (int mt = 0; mt < 4; ++mt) {
            int m = (mt + 4) * 16 + li;
            int slot = kq ^ ((m >> 1) & 3);
            xfb[mt] = *(bf16x8*)(base + m * 64 + slot * 16);
        }
        asm volatile("s_waitcnt lgkmcnt(0)" ::: "memory");
        __builtin_amdgcn_sched_barrier(0);
#pragma unroll
        for (int nt = 0; nt < 4; ++nt)
#pragma unroll
            for (int mt = 0; mt < 4; ++mt)
                acc2[mt+4][nt] = __builtin_amdgcn_mfma_f32_16x16x32_bf16(wf[nt], xfb[mt], acc2[mt+4][nt], 0, 0, 0);
        __builtin_amdgcn_s_setprio(0);
        __builtin_amdgcn_sched_barrier(0);
        __builtin_amdgcn_s_barrier();           // next buffer complete; cur reads done block-wide
        __builtin_amdgcn_sched_barrier(0);
    }
    __syncthreads();

    // ---- h2 = relu(acc2 + b2) -> bf16 -> LDS [128][512] swizzled (overwrites loop region)
#pragma unroll
    for (int mt = 0; mt < 8; ++mt)
#pragma unroll
        for (int nt = 0; nt < 4; ++nt) {
            int m = mt * 16 + li;
            int nb = wave * 64 + nt * 16 + kq * 4;
            float4 bb = *(const float4*)&b2[nb];
            float v0 = fmaxf(acc2[mt][nt][0] + bb.x, 0.f);
            float v1 = fmaxf(acc2[mt][nt][1] + bb.y, 0.f);
            float v2 = fmaxf(acc2[mt][nt][2] + bb.z, 0.f);
            float v3 = fmaxf(acc2[mt][nt][3] + bb.w, 0.f);
            uint2 pw; pw.x = pack2(v0, v1); pw.y = pack2(v2, v3);
            int addr = (m * 1024 + nb * 2) ^ ((m & 7) << 4);
            *(uint2*)(smem + addr) = pw;
        }
    __syncthreads();

    // ---- GEMM3 [128x512]@[512x48]: wave owns 16 m-rows, full K
    f32x4 acc3[3];
#pragma unroll
    for (int nt = 0; nt < 3; ++nt) acc3[nt] = (f32x4)0.f;
#pragma unroll
    for (int ks = 0; ks < 16; ++ks) {
        int k0 = ks * 32;
        int m = wave * 16 + li;
        int addr = (m * 1024 + k0 * 2 + kq * 16) ^ ((m & 7) << 4);
        bf16x8 xfr = *(bf16x8*)(smem + addr);
#pragma unroll
        for (int nt = 0; nt < 3; ++nt) {
            int col = nt * 16 + li;
            bf16x8 wfr = *(const bf16x8*)(w3t + col * 512 + k0 + kq * 8);
            acc3[nt] = __builtin_amdgcn_mfma_f32_16x16x32_bf16(wfr, xfr, acc3[nt], 0, 0, 0);
        }
    }
#pragma unroll
    for (int nt = 0; nt < 3; ++nt)
#pragma unroll
        for (int g = 0; g < 4; ++g) {
            int n = nt * 16 + kq * 4 + g;
            if (n < ODIM) {
                int m = wave * 16 + li;
                float s = acc3[nt][g] + b3[n];
                s = 1.f / (1.f + __expf(-s));
                s = fminf(fmaxf(s, 0.01f), 0.99f);
                out[(size_t)(m0 + m) * ODIM + n] = s;
            }
        }
}

extern "C" void kernel_launch(void* const* d_in, const int* in_sizes, int n_in,
                              void* d_out, int out_size, void* d_ws, size_t ws_size,
                              hipStream_t stream)
{
    const float* x     = (const float*)d_in[0];
    const float* mask  = (const float*)d_in[1];
    const float* w     = (const float*)d_in[2];
    const float* a_src = (const float*)d_in[3];
    const float* a_dst = (const float*)d_in[4];
    const float* bias  = (const float*)d_in[5];
    const float* W1    = (const float*)d_in[6];
    const float* b1    = (const float*)d_in[7];
    const float* W2    = (const float*)d_in[8];
    const float* b2    = (const float*)d_in[9];
    const float* W3    = (const float*)d_in[10];
    const float* b3    = (const float*)d_in[11];
    float* out = (float*)d_out;

    char* p = (char*)d_ws;
    short* hpT = (short*)p;  p += (size_t)BB*NH*FO*NN*2;   // 16.78 MB
    float* asrc = (float*)p; p += (size_t)BB*NH*NN*4;
    float* adst = (float*)p; p += (size_t)BB*NH*NN*4;
    float* gat  = (float*)p; p += (size_t)BB*NN*FO*4;      // 8.39 MB
    short* w1t  = (short*)p; p += (size_t)HD1*FO*2;
    short* w2f  = (short*)p; p += (size_t)HD2*HD1*2;
    short* w3t  = (short*)p; p += (size_t)48*HD2*2;
    float* wa   = (float*)p; p += 128*4;
    unsigned char* mbits = (unsigned char*)p; p += (size_t)BB*NN*64;  // 2.1 MB

    k_wa   <<<1, 64, 0, stream>>>(w, a_src, a_dst, wa);
    k_pack <<<BB*NN/4, 256, 0, stream>>>(mask, mbits);
    k_conv <<<(HD1*FO + HD2*HD1 + 48*HD2)/256, 256, 0, stream>>>(W1, W2, W3, w1t, w2f, w3t);
    k_proj2<<<dim3(NN/64, BB), 256, 0, stream>>>(x, w, bias, wa, hpT, asrc, adst, gat);
    k_attn2<<<dim3(NN/64, BB), 512, 0, stream>>>(hpT, mbits, asrc, adst, gat);
    k_mlpB <<<BB*NN/128, 512, 131072, stream>>>(gat, w1t, b1, w2f, b2, w3t, b3, out);
}